// Round 7
// baseline (126.535 us; speedup 1.0000x reference)
//
#include <hip/hip_runtime.h>

// StructuredStateSpace: h_t = A h_{t-1} + Bw x_t + Bb ; y_t = Cw h_t
// B=16, S=8192, D_IN=64, D_ST=128.  Output scale +-488, threshold 0.32 =>
// ~6.6e-4 relative accuracy: all operands f16 hi+lo pairs, 3 of 4 cross
// terms (validated r3/r4: absmax 0.156).
//
// Round-7 (= round-6 + missing U1-slot pack): warm-up runs 4 timesteps per
// sync-step using precomputed P=A^4, U-slots {A^3 Bw, A^2 Bw, A Bw, Bw},
// Bb4=(A^3+A^2+A+I)Bb (device fp32 prep, hi/lo packed, rho-permuted).
// 112 warm steps -> 28 iterations with the SAME serial cost each (4-deep
// MFMA chain + one LDS exchange + one barrier). Output region keeps
// validated q=1 steps. All accumulation chains tree-split 2+2.

#define SEQ   8192
#define DIN   64
#define LCH   32
#define NCH   (SEQ / LCH)        // 256 blocks = 1 per CU
#define WFULL 48
#define WTOT  112

typedef _Float16 v8h __attribute__((ext_vector_type(8)));
typedef __fp16   v2h __attribute__((ext_vector_type(2)));
typedef float    v4f __attribute__((ext_vector_type(4)));

#define MFMA(a, b, c) __builtin_amdgcn_mfma_f32_16x16x32_f16((a), (b), (c), 0, 0, 0)
#define PKRTZ __builtin_amdgcn_cvt_pkrtz
#define Z4 (v4f{0.f, 0.f, 0.f, 0.f})

// rho: logical l = 32*kt + 8*q + e -> physical D-row p = 16*m + 4*q + r,
// m = kt + 4*(eh&1), r = 2*(eh>>1) + (e&1), eh = e>>1.
__device__ __forceinline__ int rho_fwd(int lidx) {
  int kt = lidx >> 5, q = (lidx >> 3) & 3, e = lidx & 7;
  int eh = e >> 1;
  int m = kt + 4 * (eh & 1);
  int r = 2 * (eh >> 1) + (e & 1);
  return 16 * m + 4 * q + r;
}
__device__ __forceinline__ int rho_inv(int p) {
  int m = p >> 4, q = (p >> 2) & 3, r = p & 3;
  int eh = ((r >> 1) << 1) | (m >> 2);
  int e  = (eh << 1) | (r & 1);
  return 32 * (m & 3) + 8 * q + e;
}

__device__ __forceinline__ void pack_hl(float v, _Float16* hp, _Float16* lp) {
  _Float16 h = (_Float16)v;
  *hp = h; *lp = (_Float16)(v - (float)h);
}

// F (f16 units): Ah 0 | Al 16384 | Ph 32768 | Pl 49152 | Uh 65536 (slots
// d*8192: d0=A^3Bw d1=A^2Bw d2=ABw d3=Bw) | Ul 98304 | Cwh 131072 |
// Cwl 139264 | end 147456.  Then f32: Bbs[128], Bb4s[128], A2f[16384],
// U1f[8192], b1f[128].  Total ws = 394752 bytes.

__global__ void prep1(const float* __restrict__ A, const float* __restrict__ Bw,
                      const float* __restrict__ Bb, const float* __restrict__ Cw,
                      _Float16* __restrict__ F, float* __restrict__ Bbs,
                      float* __restrict__ A2f, float* __restrict__ U1f,
                      float* __restrict__ b1f) {
  int idx = blockIdx.x * 256 + threadIdx.x;
  if (idx < 16384) {                         // A2 = A*A
    int i = idx >> 7, j = idx & 127;
    float s = 0.f; const float* ar = A + i * 128;
    for (int k = 0; k < 128; ++k) s = fmaf(ar[k], A[k * 128 + j], s);
    A2f[idx] = s;
  } else if (idx < 24576) {                  // U1 = A*Bw
    int p = idx - 16384; int i = p >> 6, j = p & 63;
    float s = 0.f; const float* ar = A + i * 128;
    for (int k = 0; k < 128; ++k) s = fmaf(ar[k], Bw[k * 64 + j], s);
    U1f[p] = s;
  } else if (idx < 24704) {                  // b1 = A*Bb
    int i = idx - 24576;
    float s = 0.f; const float* ar = A + i * 128;
    for (int k = 0; k < 128; ++k) s = fmaf(ar[k], Bb[k], s);
    b1f[i] = s;
  } else if (idx < 41088) {                  // pack A (rho rows)
    int p = idx - 24704; int i = p >> 7, j = p & 127;
    int o = rho_fwd(i) * 128 + j;
    pack_hl(A[p], F + o, F + 16384 + o);
  } else if (idx < 49280) {                  // pack Bw -> U slot3 (rho rows)
    int p = idx - 41088; int i = p >> 6, j = p & 63;
    int o = rho_fwd(i) * 64 + j;
    pack_hl(Bw[p], F + 65536 + 3 * 8192 + o, F + 98304 + 3 * 8192 + o);
  } else if (idx < 57472) {                  // pack Cw (plain)
    int p = idx - 49280;
    pack_hl(Cw[p], F + 131072 + p, F + 139264 + p);
  } else if (idx < 57600) {                  // Bbs (rho)
    int i = idx - 57472;
    Bbs[i] = Bb[rho_inv(i)];
  }
}

__global__ void prep2(const float* __restrict__ Bw, const float* __restrict__ Bb,
                      _Float16* __restrict__ F, float* __restrict__ Bb4s,
                      const float* __restrict__ A2f, const float* __restrict__ U1f,
                      const float* __restrict__ b1f) {
  int idx = blockIdx.x * 256 + threadIdx.x;
  if (idx < 16384) {                         // P = A2*A2 -> Ph/Pl
    int i = idx >> 7, j = idx & 127;
    float s = 0.f; const float* ar = A2f + i * 128;
    for (int k = 0; k < 128; ++k) s = fmaf(ar[k], A2f[k * 128 + j], s);
    int o = rho_fwd(i) * 128 + j;
    pack_hl(s, F + 32768 + o, F + 49152 + o);
  } else if (idx < 24576) {                  // U2 = A2*Bw -> slot1
    int p = idx - 16384; int i = p >> 6, j = p & 63;
    float s = 0.f; const float* ar = A2f + i * 128;
    for (int k = 0; k < 128; ++k) s = fmaf(ar[k], Bw[k * 64 + j], s);
    int o = rho_fwd(i) * 64 + j;
    pack_hl(s, F + 65536 + 8192 + o, F + 98304 + 8192 + o);
  } else if (idx < 32768) {                  // U3 = A2*U1 -> slot0
    int p = idx - 24576; int i = p >> 6, j = p & 63;
    float s = 0.f; const float* ar = A2f + i * 128;
    for (int k = 0; k < 128; ++k) s = fmaf(ar[k], U1f[k * 64 + j], s);
    int o = rho_fwd(i) * 64 + j;
    pack_hl(s, F + 65536 + o, F + 98304 + o);
  } else if (idx < 32896) {                  // Bb4 = (Bb+b1) + A2*(Bb+b1), rho
    int i = idx - 32768;
    float s = Bb[i] + b1f[i];
    const float* ar = A2f + i * 128;
    for (int k = 0; k < 128; ++k) s = fmaf(ar[k], Bb[k] + b1f[k], s);
    Bb4s[rho_fwd(i)] = s;
  } else if (idx < 41088) {                  // pack U1 = A*Bw -> slot2 (THE FIX)
    int p = idx - 32896; int i = p >> 6, j = p & 63;
    int o = rho_fwd(i) * 64 + j;
    pack_hl(U1f[p], F + 65536 + 2 * 8192 + o, F + 98304 + 2 * 8192 + o);
  }
}

__device__ __forceinline__ void split16(const v4f* b, v8h& xh0, v8h& xh1,
                                        v8h& xl0, v8h& xl1, bool full) {
  union { v2h h2[4]; v8h h8; } H0, H1;
  H0.h2[0] = PKRTZ(b[0][0], b[0][1]); H0.h2[1] = PKRTZ(b[0][2], b[0][3]);
  H0.h2[2] = PKRTZ(b[1][0], b[1][1]); H0.h2[3] = PKRTZ(b[1][2], b[1][3]);
  H1.h2[0] = PKRTZ(b[2][0], b[2][1]); H1.h2[1] = PKRTZ(b[2][2], b[2][3]);
  H1.h2[2] = PKRTZ(b[3][0], b[3][1]); H1.h2[3] = PKRTZ(b[3][2], b[3][3]);
  xh0 = H0.h8; xh1 = H1.h8;
  if (full) {
    float r[16];
#pragma unroll
    for (int i = 0; i < 8; ++i) r[i]     = b[i >> 2][i & 3]       - (float)H0.h8[i];
#pragma unroll
    for (int i = 0; i < 8; ++i) r[8 + i] = b[2 + (i >> 2)][i & 3] - (float)H1.h8[i];
    union { v2h h2[4]; v8h h8; } L0, L1;
    L0.h2[0] = PKRTZ(r[0], r[1]);   L0.h2[1] = PKRTZ(r[2], r[3]);
    L0.h2[2] = PKRTZ(r[4], r[5]);   L0.h2[3] = PKRTZ(r[6], r[7]);
    L1.h2[0] = PKRTZ(r[8], r[9]);   L1.h2[1] = PKRTZ(r[10], r[11]);
    L1.h2[2] = PKRTZ(r[12], r[13]); L1.h2[3] = PKRTZ(r[14], r[15]);
    xl0 = L0.h8; xl1 = L1.h8;
  }
}

__global__ __launch_bounds__(256, 1) void ssm_kernel(
    const float* __restrict__ x, float* __restrict__ y,
    const _Float16* __restrict__ F, const float* __restrict__ Bbs,
    const float* __restrict__ Bb4s) {
  const int tid = threadIdx.x;
  const int wv  = tid >> 6;      // wave 0..3: owns m in {wv, wv+4}; emits tile wv
  const int l   = tid & 63;
  const int n   = l & 15;        // batch
  const int q   = l >> 4;        // lane group
  const int c   = blockIdx.x;
  const int t0  = c * LCH, te = t0 + LCH;
  const int ts  = (t0 > WTOT)  ? (t0 - WTOT)  : 0;
  const int tf  = (t0 > WFULL) ? (t0 - WFULL) : 0;
  const int nwarm = (t0 - ts) >> 2;

  const _Float16* Ah = F;
  const _Float16* Al = F + 16384;
  const _Float16* Ph = F + 32768;
  const _Float16* Pl = F + 49152;
  const _Float16* Uh = F + 65536;
  const _Float16* Ul = F + 98304;
  const _Float16* Ch = F + 131072;
  const _Float16* Cl = F + 139264;

  __shared__ _Float16 hx[2][2][4][512];   // [parity][hi/lo][kt][lane*8]

  const float* xb = x + (size_t)n * (SEQ * DIN) + 8 * q;
  float* yb = y + (size_t)n * (SEQ * DIN);

  v8h hf[4], hlo[4];
#pragma unroll
  for (int kt = 0; kt < 4; ++kt) { hf[kt] = v8h{}; hlo[kt] = v8h{}; }

  // pack this wave's two D-tiles into B-frag kt=wv and write to LDS
  auto xwrite = [&](int pr, const v4f& a0, const v4f& a1, bool full) {
    union { v2h h2[4]; v8h h8; } U;
    U.h2[0] = PKRTZ(a0[0], a0[1]); U.h2[1] = PKRTZ(a1[0], a1[1]);
    U.h2[2] = PKRTZ(a0[2], a0[3]); U.h2[3] = PKRTZ(a1[2], a1[3]);
    *(v8h*)&hx[pr][0][wv][l * 8] = U.h8;
    if (full) {
      float r0 = a0[0] - (float)U.h8[0], r1 = a0[1] - (float)U.h8[1];
      float r2 = a1[0] - (float)U.h8[2], r3 = a1[1] - (float)U.h8[3];
      float r4 = a0[2] - (float)U.h8[4], r5 = a0[3] - (float)U.h8[5];
      float r6 = a1[2] - (float)U.h8[6], r7 = a1[3] - (float)U.h8[7];
      union { v2h h2[4]; v8h h8; } L;
      L.h2[0] = PKRTZ(r0, r1); L.h2[1] = PKRTZ(r2, r3);
      L.h2[2] = PKRTZ(r4, r5); L.h2[3] = PKRTZ(r6, r7);
      *(v8h*)&hx[pr][1][wv][l * 8] = L.h8;
    }
  };

  // ================= warm-up: q=4 iterations =================
  if (nwarm > 0) {
    v8h pfh[2][4], pfl[2][4], uwh[4][2][2], uwl[4][2][2];
    v4f bb4[2];
#pragma unroll
    for (int i = 0; i < 2; ++i) {
      int row = 16 * (wv + 4 * i) + n;
#pragma unroll
      for (int kt = 0; kt < 4; ++kt) {
        pfh[i][kt] = *(const v8h*)(Ph + row * 128 + 32 * kt + 8 * q);
        pfl[i][kt] = *(const v8h*)(Pl + row * 128 + 32 * kt + 8 * q);
      }
#pragma unroll
      for (int d = 0; d < 4; ++d)
#pragma unroll
        for (int k2 = 0; k2 < 2; ++k2) {
          uwh[d][i][k2] = *(const v8h*)(Uh + d * 8192 + row * 64 + 32 * k2 + 8 * q);
          uwl[d][i][k2] = *(const v8h*)(Ul + d * 8192 + row * 64 + 32 * k2 + 8 * q);
        }
      bb4[i] = *(const v4f*)(Bb4s + 16 * (wv + 4 * i) + 4 * q);
    }

    v4f xw[4][4];
    v4f u4A[2], u4B[2];
    auto loadx4 = [&](int tt) {
#pragma unroll
      for (int d = 0; d < 4; ++d) {
        const float* p = xb + (size_t)(tt + d) * DIN;
        xw[d][0] = *(const v4f*)(p);
        xw[d][1] = *(const v4f*)(p + 4);
        xw[d][2] = *(const v4f*)(p + 32);
        xw[d][3] = *(const v4f*)(p + 36);
      }
    };
    auto build_u4 = [&](bool full) {
      v4f a1[2] = {bb4[0], bb4[1]};
      v4f a2[2] = {Z4, Z4};
      v4f b1v[2] = {Z4, Z4};
      v4f b2v[2] = {Z4, Z4};
#pragma unroll
      for (int d = 0; d < 4; ++d) {
        v8h xh0, xh1, xl0, xl1;
        split16(xw[d], xh0, xh1, xl0, xl1, full);
        v4f* ta = (d < 2) ? a1 : a2;
        v4f* tb = (d < 2) ? b1v : b2v;
#pragma unroll
        for (int i = 0; i < 2; ++i) {
          ta[i] = MFMA(uwh[d][i][0], xh0, ta[i]);
          ta[i] = MFMA(uwh[d][i][1], xh1, ta[i]);
          if (full) {
            tb[i] = MFMA(uwl[d][i][0], xh0, tb[i]);
            tb[i] = MFMA(uwl[d][i][1], xh1, tb[i]);
            tb[i] = MFMA(uwh[d][i][0], xl0, tb[i]);
            tb[i] = MFMA(uwh[d][i][1], xl1, tb[i]);
          }
        }
      }
#pragma unroll
      for (int i = 0; i < 2; ++i) { u4A[i] = a1[i] + a2[i]; u4B[i] = b1v[i] + b2v[i]; }
    };

    loadx4(ts);
    build_u4(ts >= tf);            // u for iteration 0
    loadx4(ts + 4);                // x for iteration 1

    for (int j = 0; j < nwarm; ++j) {
      const int  pr    = j & 1;
      const bool fullj = (ts + 4 * j) >= tf;
      v4f acc[2];
#pragma unroll
      for (int i = 0; i < 2; ++i) {
        v4f a = MFMA(pfh[i][0], hf[0], u4A[i]);
        a     = MFMA(pfh[i][1], hf[1], a);
        v4f b = MFMA(pfh[i][2], hf[2], Z4);
        b     = MFMA(pfh[i][3], hf[3], b);
        if (fullj) {
          v4f c2a = MFMA(pfl[i][0], hf[0], u4B[i]);
          c2a     = MFMA(pfl[i][1], hf[1], c2a);
          v4f c2b = MFMA(pfl[i][2], hf[2], Z4);
          c2b     = MFMA(pfl[i][3], hf[3], c2b);
          v4f c3a = MFMA(pfh[i][0], hlo[0], Z4);
          c3a     = MFMA(pfh[i][1], hlo[1], c3a);
          v4f c3b = MFMA(pfh[i][2], hlo[2], Z4);
          c3b     = MFMA(pfh[i][3], hlo[3], c3b);
          acc[i] = (a + b) + (c2a + c2b) + (c3a + c3b);
        } else {
          acc[i] = a + b;
        }
      }
      if (j + 1 < nwarm) {
        build_u4((ts + 4 * (j + 1)) >= tf);   // u for iteration j+1
        loadx4(ts + 4 * (j + 2));             // x for iteration j+2 (<= t0+4, in range)
      }
      xwrite(pr, acc[0], acc[1], fullj);
      __syncthreads();
#pragma unroll
      for (int kt = 0; kt < 4; ++kt) hf[kt] = *(const v8h*)&hx[pr][0][kt][l * 8];
      if (fullj) {
#pragma unroll
        for (int kt = 0; kt < 4; ++kt) hlo[kt] = *(const v8h*)&hx[pr][1][kt][l * 8];
      }
    }
  }

  asm volatile("" ::: "memory");   // keep output-weight loads out of warm loop

  // ================= output region: q=1 steps (validated r4 numerics) =======
  v8h afh[2][4], afl[2][4], bwh[2][2], bwl[2][2], cwh[4], cwl[4];
  v4f bb2[2];
#pragma unroll
  for (int i = 0; i < 2; ++i) {
    int row = 16 * (wv + 4 * i) + n;
#pragma unroll
    for (int kt = 0; kt < 4; ++kt) {
      afh[i][kt] = *(const v8h*)(Ah + row * 128 + 32 * kt + 8 * q);
      afl[i][kt] = *(const v8h*)(Al + row * 128 + 32 * kt + 8 * q);
    }
#pragma unroll
    for (int k2 = 0; k2 < 2; ++k2) {
      bwh[i][k2] = *(const v8h*)(Uh + 3 * 8192 + row * 64 + 32 * k2 + 8 * q);
      bwl[i][k2] = *(const v8h*)(Ul + 3 * 8192 + row * 64 + 32 * k2 + 8 * q);
    }
    bb2[i] = *(const v4f*)(Bbs + 16 * (wv + 4 * i) + 4 * q);
  }
  {
    int row = 16 * wv + n;
#pragma unroll
    for (int kt = 0; kt < 4; ++kt) {
      cwh[kt] = *(const v8h*)(Ch + row * 128 + 32 * kt + 8 * q);
      cwl[kt] = *(const v8h*)(Cl + row * 128 + 32 * kt + 8 * q);
    }
  }

  v4f bufA[4], bufB[4];
  v4f uA[2], uB[2];
  auto loadx = [&](v4f(&buf)[4], int t) {
    const float* p = xb + (size_t)t * DIN;
    buf[0] = *(const v4f*)(p);
    buf[1] = *(const v4f*)(p + 4);
    buf[2] = *(const v4f*)(p + 32);
    buf[3] = *(const v4f*)(p + 36);
  };
  auto build_u = [&](const v4f(&b)[4]) {
    v8h xh0, xh1, xl0, xl1;
    split16(b, xh0, xh1, xl0, xl1, true);
#pragma unroll
    for (int i = 0; i < 2; ++i) {
      v4f a = bb2[i];
      a = MFMA(bwh[i][0], xh0, a);
      a = MFMA(bwh[i][1], xh1, a);
      uA[i] = a;
      v4f bacc = MFMA(bwl[i][0], xh0, Z4);
      bacc = MFMA(bwl[i][1], xh1, bacc);
      v4f bacc2 = MFMA(bwh[i][0], xl0, Z4);
      bacc2 = MFMA(bwh[i][1], xl1, bacc2);
      uB[i] = bacc + bacc2;
    }
  };
  auto emit_y = [&](int t) {
    v4f e1a = MFMA(cwh[1], hf[1], MFMA(cwh[0], hf[0], Z4));
    v4f e1b = MFMA(cwh[3], hf[3], MFMA(cwh[2], hf[2], Z4));
    v4f e2a = MFMA(cwh[1], hlo[1], MFMA(cwh[0], hlo[0], Z4));
    v4f e2b = MFMA(cwh[3], hlo[3], MFMA(cwh[2], hlo[2], Z4));
    v4f e3a = MFMA(cwl[1], hf[1], MFMA(cwl[0], hf[0], Z4));
    v4f e3b = MFMA(cwl[3], hf[3], MFMA(cwl[2], hf[2], Z4));
    v4f r = (e1a + e1b) + (e2a + e2b) + (e3a + e3b);
    *(v4f*)(yb + (size_t)t * DIN + 16 * wv + 4 * q) = r;
  };
  auto step_full = [&](int t, v4f(&bsrc)[4], v4f(&bld)[4], int pr, bool emit) {
    if (emit) emit_y(t - 1);
    v4f acc[2];
#pragma unroll
    for (int i = 0; i < 2; ++i) {
      v4f a = MFMA(afh[i][0], hf[0], uA[i]);
      a     = MFMA(afh[i][1], hf[1], a);
      v4f b = MFMA(afh[i][2], hf[2], Z4);
      b     = MFMA(afh[i][3], hf[3], b);
      v4f c2a = MFMA(afl[i][0], hf[0], uB[i]);
      c2a     = MFMA(afl[i][1], hf[1], c2a);
      v4f c2b = MFMA(afl[i][2], hf[2], Z4);
      c2b     = MFMA(afl[i][3], hf[3], c2b);
      v4f c3a = MFMA(afh[i][0], hlo[0], Z4);
      c3a     = MFMA(afh[i][1], hlo[1], c3a);
      v4f c3b = MFMA(afh[i][2], hlo[2], Z4);
      c3b     = MFMA(afh[i][3], hlo[3], c3b);
      acc[i] = (a + b) + (c2a + c2b) + (c3a + c3b);
    }
    build_u(bsrc);                 // u_{t+1}, off critical path
    int tn = t + 2; if (tn > SEQ - 1) tn = SEQ - 1;
    loadx(bld, tn);
    xwrite(pr, acc[0], acc[1], true);
    __syncthreads();
#pragma unroll
    for (int kt = 0; kt < 4; ++kt) {
      hf[kt]  = *(const v8h*)&hx[pr][0][kt][l * 8];
      hlo[kt] = *(const v8h*)&hx[pr][1][kt][l * 8];
    }
  };

  loadx(bufA, t0);
  loadx(bufB, t0 + 1);
  build_u(bufA);
  for (int t = t0; t < te; t += 2) {
    step_full(t,     bufB, bufA, 0, t > t0);
    step_full(t + 1, bufA, bufB, 1, true);
  }
  emit_y(te - 1);
}

extern "C" void kernel_launch(void* const* d_in, const int* in_sizes, int n_in,
                              void* d_out, int out_size, void* d_ws, size_t ws_size,
                              hipStream_t stream) {
  const float* x  = (const float*)d_in[0];
  const float* A  = (const float*)d_in[1];
  const float* Bw = (const float*)d_in[2];
  const float* Bb = (const float*)d_in[3];
  const float* Cw = (const float*)d_in[4];
  float* y = (float*)d_out;

  _Float16* F    = (_Float16*)d_ws;
  float*    Bbs  = (float*)(F + 147456);
  float*    Bb4s = Bbs + 128;
  float*    A2f  = Bb4s + 128;
  float*    U1f  = A2f + 16384;
  float*    b1f  = U1f + 8192;     // ws requirement: 394752 bytes

  prep1<<<225, 256, 0, stream>>>(A, Bw, Bb, Cw, F, Bbs, A2f, U1f, b1f);
  prep2<<<161, 256, 0, stream>>>(Bw, Bb, F, Bb4s, A2f, U1f, b1f);
  ssm_kernel<<<NCH, 256, 0, stream>>>(x, y, F, Bbs, Bb4s);
}